// Round 1
// baseline (1352.313 us; speedup 1.0000x reference)
//
#include <hip/hip_runtime.h>
#include <hip/hip_bf16.h>
#include <math.h>

#define D 128
#define NEG 0.2f
#define EPSV 1e-16f

__device__ __forceinline__ float lrelu(float v){ return v >= 0.f ? v : NEG*v; }

// ---------------- CSR build (once per call; graph constant across layers) ----------------
__global__ void count_kernel(const int* __restrict__ edst, int E, int N, int* __restrict__ deg){
  int i = blockIdx.x*blockDim.x + threadIdx.x;
  int tot = E + N;
  if (i >= tot) return;
  int d = (i < E) ? edst[i] : (i - E);
  atomicAdd(&deg[d], 1);
}

__global__ void scan_kernel(const int* __restrict__ deg, int N, int* __restrict__ row_ptr, int* __restrict__ cursor){
  __shared__ int part[1024];
  const int CH = 16;                 // 1024*16 = 16384 >= N
  int t = threadIdx.x;
  int base = t*CH;
  int local[CH]; int s = 0;
  #pragma unroll
  for (int j=0;j<CH;j++){ int idx=base+j; int v = (idx<N)? deg[idx] : 0; local[j]=s; s+=v; }
  part[t]=s; __syncthreads();
  for (int off=1; off<1024; off<<=1){
    int v = (t>=off)? part[t-off] : 0;
    __syncthreads();
    part[t]+=v;
    __syncthreads();
  }
  int cb = (t==0)? 0 : part[t-1];
  #pragma unroll
  for (int j=0;j<CH;j++){ int idx=base+j; if(idx<N){ int r=cb+local[j]; row_ptr[idx]=r; cursor[idx]=r; } }
  if (t==1023) row_ptr[N]=part[1023];
}

__global__ void scatter_kernel(const int* __restrict__ esrc, const int* __restrict__ edst,
                               int E, int N, int* __restrict__ cursor, int* __restrict__ csr_src){
  int i = blockIdx.x*blockDim.x + threadIdx.x;
  int tot = E + N;
  if (i>=tot) return;
  int s, d2;
  if (i<E){ s=esrc[i]; d2=edst[i]; } else { s=i-E; d2=i-E; }
  int pos = atomicAdd(&cursor[d2],1);
  csr_src[pos]=s;
}

// ---------------- Per-layer linear: h = x@W, es/ed attention dots ----------------
// Block = 128 threads, one W column per lane (128 VGPRs of W), x rows are wave-uniform
// scalar loads. NPB nodes per block.
template<int HEADS, int NPB>
__launch_bounds__(128, 2)
__global__ void linear_kernel(const float* __restrict__ x, const float* __restrict__ W,
                              const float* __restrict__ asrc, const float* __restrict__ adst,
                              int N, float* __restrict__ h, float* __restrict__ es, float* __restrict__ ed){
  int col = threadIdx.x;
  float w[D];
  #pragma unroll
  for (int k=0;k<D;k++) w[k] = W[k*D + col];
  float av = asrc[col], bv = adst[col];
  __shared__ float partsE[2], partsD[2];
  int n0 = blockIdx.x * NPB;
  for (int i=0;i<NPB;i++){
    int n = n0 + i;
    if (n >= N) break;                    // uniform across block
    const float* xr = x + (size_t)n*D;
    float a0=0.f,a1=0.f,a2=0.f,a3=0.f;
    #pragma unroll
    for (int k=0;k<D;k+=4){
      a0 += xr[k+0]*w[k+0];
      a1 += xr[k+1]*w[k+1];
      a2 += xr[k+2]*w[k+2];
      a3 += xr[k+3]*w[k+3];
    }
    float acc = (a0+a1)+(a2+a3);
    h[(size_t)n*D + col] = acc;
    float ps = acc*av, pd = acc*bv;
    if constexpr (HEADS==4){
      #pragma unroll
      for (int off=16; off; off>>=1){ ps += __shfl_xor(ps, off, 32); pd += __shfl_xor(pd, off, 32); }
      if ((col&31)==0){ es[n*4 + (col>>5)] = ps; ed[n*4 + (col>>5)] = pd; }
    } else {
      #pragma unroll
      for (int off=32; off; off>>=1){ ps += __shfl_xor(ps, off, 64); pd += __shfl_xor(pd, off, 64); }
      int wv = col>>6;
      if ((col&63)==0){ partsE[wv]=ps; partsD[wv]=pd; }
      __syncthreads();
      if (col==0){ es[n] = partsE[0]+partsE[1]; ed[n] = partsD[0]+partsD[1]; }
      __syncthreads();
    }
  }
}

// ---------------- Per-layer aggregation: segment softmax + weighted sum ----------------
// One wave per dst node. Phase 1: edge-parallel max per head. Phase 2: sequential over
// edges, each lane owns 2 of 128 channels. No atomics.
template<int HEADS, bool RELU>
__launch_bounds__(256, 4)
__global__ void aggregate_kernel(const float* __restrict__ h, const float* __restrict__ es, const float* __restrict__ ed,
                                 const int* __restrict__ row_ptr, const int* __restrict__ csr_src,
                                 const float* __restrict__ bias, float* __restrict__ out, int N){
  int lane = threadIdx.x & 63;
  int wid  = threadIdx.x >> 6;
  int n = blockIdx.x*4 + wid;
  if (n >= N) return;
  int start = row_ptr[n], end = row_ptr[n+1];

  float edn[HEADS];
  #pragma unroll
  for (int hh=0;hh<HEADS;hh++) edn[hh] = ed[n*HEADS+hh];

  // phase 1: max over incoming edges, per head
  float mx[HEADS];
  #pragma unroll
  for (int hh=0;hh<HEADS;hh++) mx[hh] = -1e30f;
  for (int e = start + lane; e < end; e += 64){
    int s = csr_src[e];
    #pragma unroll
    for (int hh=0;hh<HEADS;hh++){
      float v = lrelu(es[s*HEADS+hh] + edn[hh]);
      mx[hh] = fmaxf(mx[hh], v);
    }
  }
  #pragma unroll
  for (int hh=0;hh<HEADS;hh++){
    #pragma unroll
    for (int off=32; off; off>>=1) mx[hh] = fmaxf(mx[hh], __shfl_xor(mx[hh], off, 64));
  }
  int myh = 0;
  float m_own = mx[0], edn_own = edn[0];
  if constexpr (HEADS==4){
    myh = lane >> 4;
    m_own   = (lane<16)? mx[0]  : (lane<32)? mx[1]  : (lane<48)? mx[2]  : mx[3];
    edn_own = (lane<16)? edn[0] : (lane<32)? edn[1] : (lane<48)? edn[2] : edn[3];
  }

  // phase 2: sequential over edges; lane owns channels (2*lane, 2*lane+1)
  float accx=0.f, accy=0.f, z=0.f;
  int c0 = lane*2;
  for (int e = start; e < end; e++){
    int s = csr_src[e];
    float ev = lrelu(es[s*HEADS + myh] + edn_own);
    float pm = expf(ev - m_own);
    z += pm;
    const float2 hv = *reinterpret_cast<const float2*>(h + (size_t)s*D + c0);
    accx += pm*hv.x;
    accy += pm*hv.y;
  }
  float inv = 1.f/(z + EPSV);
  const float2 bv = *reinterpret_cast<const float2*>(bias + c0);
  float ox = accx*inv + bv.x, oy = accy*inv + bv.y;
  if (RELU){ ox = fmaxf(ox,0.f); oy = fmaxf(oy,0.f); }
  *reinterpret_cast<float2*>(out + (size_t)n*D + c0) = make_float2(ox, oy);
}

extern "C" void kernel_launch(void* const* d_in, const int* in_sizes, int n_in,
                              void* d_out, int out_size, void* d_ws, size_t ws_size,
                              hipStream_t stream) {
  const float* x          = (const float*)d_in[0];
  const int*   ei         = (const int*)d_in[1];
  const float* Ws         = (const float*)d_in[2];
  const float* a_src      = (const float*)d_in[3];
  const float* a_dst      = (const float*)d_in[4];
  const float* bs         = (const float*)d_in[5];
  const float* W_last     = (const float*)d_in[6];
  const float* a_src_last = (const float*)d_in[7];
  const float* a_dst_last = (const float*)d_in[8];
  const float* b_last     = (const float*)d_in[9];

  int N = in_sizes[0]/D;
  int E = in_sizes[1]/2;
  int L = in_sizes[2]/(D*D);
  const int* esrc = ei;
  const int* edst = ei + E;

  // workspace layout
  char* ws = (char*)d_ws;
  float* h   = (float*)ws;  ws += (size_t)N*D*sizeof(float);
  float* xb0 = (float*)ws;  ws += (size_t)N*D*sizeof(float);
  float* xb1 = (float*)ws;  ws += (size_t)N*D*sizeof(float);
  float* es  = (float*)ws;  ws += (size_t)N*4*sizeof(float);
  float* ed  = (float*)ws;  ws += (size_t)N*4*sizeof(float);
  int* deg     = (int*)ws;  ws += (size_t)N*sizeof(int);
  int* row_ptr = (int*)ws;  ws += (size_t)(N+1)*sizeof(int);
  int* cursor  = (int*)ws;  ws += (size_t)N*sizeof(int);
  int* csr_src = (int*)ws;  ws += (size_t)(E+N)*sizeof(int);

  int tot = E + N;
  hipMemsetAsync(deg, 0, (size_t)N*sizeof(int), stream);
  count_kernel<<<(tot+255)/256, 256, 0, stream>>>(edst, E, N, deg);
  scan_kernel<<<1, 1024, 0, stream>>>(deg, N, row_ptr, cursor);
  scatter_kernel<<<(tot+255)/256, 256, 0, stream>>>(esrc, edst, E, N, cursor, csr_src);

  const int NPB = 16;
  int gA = (N + NPB - 1)/NPB;
  int gB = (N + 3)/4;

  const float* xin = x;
  for (int l=0; l<L; l++){
    linear_kernel<4,NPB><<<gA, 128, 0, stream>>>(xin, Ws + (size_t)l*D*D,
                                                 a_src + (size_t)l*128, a_dst + (size_t)l*128,
                                                 N, h, es, ed);
    float* xout = (l & 1) ? xb1 : xb0;
    aggregate_kernel<4,true><<<gB, 256, 0, stream>>>(h, es, ed, row_ptr, csr_src,
                                                     bs + (size_t)l*D, xout, N);
    xin = xout;
  }
  linear_kernel<1,NPB><<<gA, 128, 0, stream>>>(xin, W_last, a_src_last, a_dst_last, N, h, es, ed);
  aggregate_kernel<1,false><<<gB, 256, 0, stream>>>(h, es, ed, row_ptr, csr_src,
                                                    b_last, (float*)d_out, N);
}

// Round 2
// 828.759 us; speedup vs baseline: 1.6317x; 1.6317x over previous
//
#include <hip/hip_runtime.h>
#include <hip/hip_bf16.h>
#include <math.h>

#define D 128
#define NEG 0.2f
#define EPSV 1e-16f

// ---------------- CSR build (once per call; graph constant across layers) ----------------
__global__ void count_kernel(const int* __restrict__ edst, int E, int N, int* __restrict__ deg){
  int i = blockIdx.x*blockDim.x + threadIdx.x;
  int tot = E + N;
  if (i >= tot) return;
  int d = (i < E) ? edst[i] : (i - E);
  atomicAdd(&deg[d], 1);
}

__global__ void scan_kernel(const int* __restrict__ deg, int N, int* __restrict__ row_ptr, int* __restrict__ cursor){
  __shared__ int part[1024];
  const int CH = 16;                 // 1024*16 = 16384 >= N
  int t = threadIdx.x;
  int base = t*CH;
  int local[CH]; int s = 0;
  #pragma unroll
  for (int j=0;j<CH;j++){ int idx=base+j; int v = (idx<N)? deg[idx] : 0; local[j]=s; s+=v; }
  part[t]=s; __syncthreads();
  for (int off=1; off<1024; off<<=1){
    int v = (t>=off)? part[t-off] : 0;
    __syncthreads();
    part[t]+=v;
    __syncthreads();
  }
  int cb = (t==0)? 0 : part[t-1];
  #pragma unroll
  for (int j=0;j<CH;j++){ int idx=base+j; if(idx<N){ int r=cb+local[j]; row_ptr[idx]=r; cursor[idx]=r; } }
  if (t==1023) row_ptr[N]=part[1023];
}

__global__ void scatter_kernel(const int* __restrict__ esrc, const int* __restrict__ edst,
                               int E, int N, int* __restrict__ cursor, int* __restrict__ csr_src){
  int i = blockIdx.x*blockDim.x + threadIdx.x;
  int tot = E + N;
  if (i>=tot) return;
  int s, d2;
  if (i<E){ s=esrc[i]; d2=edst[i]; } else { s=i-E; d2=i-E; }
  int pos = atomicAdd(&cursor[d2],1);
  csr_src[pos]=s;
}

// ---------------- Per-layer linear: h = x@W, es/ed attention dots ----------------
// Loop-interchanged: each lane owns one W column position but accumulates NPB node
// outputs; W[k,:] loaded ONCE per block per k (single-use, no 128-deep live range),
// x rows are wave-uniform scalar loads. FMA:VMEM = 2*NPB : 1.
template<int HEADS, int NPB>
__launch_bounds__(128, 4)
__global__ void linear_kernel(const float* __restrict__ x, const float* __restrict__ W,
                              const float* __restrict__ asrc, const float* __restrict__ adst,
                              int N, float* __restrict__ h, float* __restrict__ es, float* __restrict__ ed){
  const int col = threadIdx.x;
  const int n0  = blockIdx.x * NPB;
  const float av = asrc[col], bv = adst[col];

  const float* xp[NPB];
  #pragma unroll
  for (int j=0;j<NPB;j++){
    int nj = n0 + j; if (nj > N-1) nj = N-1;
    xp[j] = x + (size_t)nj * D;
  }

  float acc[NPB];
  #pragma unroll
  for (int j=0;j<NPB;j++) acc[j]=0.f;

  #pragma unroll 8
  for (int k=0;k<D;k++){
    const float wv = W[(size_t)k*D + col];
    #pragma unroll
    for (int j=0;j<NPB;j++) acc[j] = fmaf(xp[j][k], wv, acc[j]);
  }

  if constexpr (HEADS==4){
    #pragma unroll
    for (int j=0;j<NPB;j++){
      const int n = n0 + j;
      if (n >= N) break;
      h[(size_t)n*D + col] = acc[j];
      float ps = acc[j]*av, pd = acc[j]*bv;
      #pragma unroll
      for (int off=16; off; off>>=1){ ps += __shfl_xor(ps, off, 32); pd += __shfl_xor(pd, off, 32); }
      if ((col&31)==0){ es[n*4 + (col>>5)] = ps; ed[n*4 + (col>>5)] = pd; }
    }
  } else {
    __shared__ float pE[2][NPB], pD[2][NPB];
    #pragma unroll
    for (int j=0;j<NPB;j++){
      const int n = n0 + j;
      if (n >= N) break;
      h[(size_t)n*D + col] = acc[j];
      float ps = acc[j]*av, pd = acc[j]*bv;
      #pragma unroll
      for (int off=32; off; off>>=1){ ps += __shfl_xor(ps, off, 64); pd += __shfl_xor(pd, off, 64); }
      if ((threadIdx.x&63)==0){ pE[threadIdx.x>>6][j]=ps; pD[threadIdx.x>>6][j]=pd; }
    }
    __syncthreads();
    if (col < NPB && n0 + col < N){
      es[n0+col] = pE[0][col]+pE[1][col];
      ed[n0+col] = pD[0][col]+pD[1][col];
    }
  }
}

// ---------------- Per-layer aggregation: segment softmax + weighted sum ----------------
// One wave per dst node, single pass (no max-subtraction: e is O(1) here, exp() clamped
// at 80 for overflow safety; mathematically identical softmax). Lane owns 2 channels.
// Edge loop hand-unrolled x2 for two h-gathers in flight.
template<int HEADS, bool RELU>
__launch_bounds__(256, 8)
__global__ void aggregate_kernel(const float* __restrict__ h, const float* __restrict__ es, const float* __restrict__ ed,
                                 const int* __restrict__ row_ptr, const int* __restrict__ csr_src,
                                 const float* __restrict__ bias, float* __restrict__ out, int N){
  const int lane = threadIdx.x & 63;
  const int wid  = threadIdx.x >> 6;
  const int n = blockIdx.x*4 + wid;
  if (n >= N) return;
  const int start = row_ptr[n], end = row_ptr[n+1];

  int myh = 0;
  if constexpr (HEADS==4) myh = lane >> 4;
  const float edn = ed[n*HEADS + myh];

  const int c0 = lane*2;
  float accx=0.f, accy=0.f, z=0.f;
  int e = start;
  for (; e+2 <= end; e+=2){
    const int s0 = csr_src[e], s1 = csr_src[e+1];
    float e0 = es[s0*HEADS+myh] + edn; e0 = (e0>=0.f)? e0 : NEG*e0; e0 = fminf(e0, 80.f);
    float e1 = es[s1*HEADS+myh] + edn; e1 = (e1>=0.f)? e1 : NEG*e1; e1 = fminf(e1, 80.f);
    const float p0 = __expf(e0), p1 = __expf(e1);
    const float2 h0 = *reinterpret_cast<const float2*>(h + (size_t)s0*D + c0);
    const float2 h1 = *reinterpret_cast<const float2*>(h + (size_t)s1*D + c0);
    z += p0 + p1;
    accx = fmaf(p0, h0.x, accx); accx = fmaf(p1, h1.x, accx);
    accy = fmaf(p0, h0.y, accy); accy = fmaf(p1, h1.y, accy);
  }
  if (e < end){
    const int s0 = csr_src[e];
    float e0 = es[s0*HEADS+myh] + edn; e0 = (e0>=0.f)? e0 : NEG*e0; e0 = fminf(e0, 80.f);
    const float p0 = __expf(e0);
    const float2 h0 = *reinterpret_cast<const float2*>(h + (size_t)s0*D + c0);
    z += p0;
    accx = fmaf(p0, h0.x, accx);
    accy = fmaf(p0, h0.y, accy);
  }
  const float inv = 1.f/(z + EPSV);
  const float2 bv = *reinterpret_cast<const float2*>(bias + c0);
  float ox = fmaf(accx, inv, bv.x), oy = fmaf(accy, inv, bv.y);
  if (RELU){ ox = fmaxf(ox,0.f); oy = fmaxf(oy,0.f); }
  *reinterpret_cast<float2*>(out + (size_t)n*D + c0) = make_float2(ox, oy);
}

extern "C" void kernel_launch(void* const* d_in, const int* in_sizes, int n_in,
                              void* d_out, int out_size, void* d_ws, size_t ws_size,
                              hipStream_t stream) {
  const float* x          = (const float*)d_in[0];
  const int*   ei         = (const int*)d_in[1];
  const float* Ws         = (const float*)d_in[2];
  const float* a_src      = (const float*)d_in[3];
  const float* a_dst      = (const float*)d_in[4];
  const float* bs         = (const float*)d_in[5];
  const float* W_last     = (const float*)d_in[6];
  const float* a_src_last = (const float*)d_in[7];
  const float* a_dst_last = (const float*)d_in[8];
  const float* b_last     = (const float*)d_in[9];

  int N = in_sizes[0]/D;
  int E = in_sizes[1]/2;
  int L = in_sizes[2]/(D*D);
  const int* esrc = ei;
  const int* edst = ei + E;

  // workspace layout
  char* ws = (char*)d_ws;
  float* h   = (float*)ws;  ws += (size_t)N*D*sizeof(float);
  float* xb0 = (float*)ws;  ws += (size_t)N*D*sizeof(float);
  float* xb1 = (float*)ws;  ws += (size_t)N*D*sizeof(float);
  float* es  = (float*)ws;  ws += (size_t)N*4*sizeof(float);
  float* ed  = (float*)ws;  ws += (size_t)N*4*sizeof(float);
  int* deg     = (int*)ws;  ws += (size_t)N*sizeof(int);
  int* row_ptr = (int*)ws;  ws += (size_t)(N+1)*sizeof(int);
  int* cursor  = (int*)ws;  ws += (size_t)N*sizeof(int);
  int* csr_src = (int*)ws;  ws += (size_t)(E+N)*sizeof(int);

  int tot = E + N;
  hipMemsetAsync(deg, 0, (size_t)N*sizeof(int), stream);
  count_kernel<<<(tot+255)/256, 256, 0, stream>>>(edst, E, N, deg);
  scan_kernel<<<1, 1024, 0, stream>>>(deg, N, row_ptr, cursor);
  scatter_kernel<<<(tot+255)/256, 256, 0, stream>>>(esrc, edst, E, N, cursor, csr_src);

  const int NPB = 8;
  int gA = (N + NPB - 1)/NPB;
  int gB = (N + 3)/4;

  const float* xin = x;
  for (int l=0; l<L; l++){
    linear_kernel<4,NPB><<<gA, 128, 0, stream>>>(xin, Ws + (size_t)l*D*D,
                                                 a_src + (size_t)l*128, a_dst + (size_t)l*128,
                                                 N, h, es, ed);
    float* xout = (l & 1) ? xb1 : xb0;
    aggregate_kernel<4,true><<<gB, 256, 0, stream>>>(h, es, ed, row_ptr, csr_src,
                                                     bs + (size_t)l*D, xout, N);
    xin = xout;
  }
  linear_kernel<1,NPB><<<gA, 128, 0, stream>>>(xin, W_last, a_src_last, a_dst_last, N, h, es, ed);
  aggregate_kernel<1,false><<<gB, 256, 0, stream>>>(h, es, ed, row_ptr, csr_src,
                                                    b_last, (float*)d_out, N);
}